// Round 5
// baseline (214.926 us; speedup 1.0000x reference)
//
#include <hip/hip_runtime.h>
#include <hip/hip_bf16.h>

typedef __hip_bfloat16 bf16;
typedef _Float16 h16;
typedef __attribute__((ext_vector_type(8))) _Float16 h16x8;
typedef __attribute__((ext_vector_type(4))) float f32x4;
typedef __attribute__((ext_vector_type(16))) float f32x16;

__device__ __forceinline__ float lrelu(float x) { return fmaxf(x, 0.1f * x); }
__device__ __forceinline__ float ldE(const void* p, long i, int f32) {
    return f32 ? ((const float*)p)[i] : __bfloat162float(((const bf16*)p)[i]);
}
__device__ __forceinline__ uint2 pack4(float a, float b, float c, float d) {
    union { _Float16 h[4]; uint2 u; } t;
    t.h[0] = (_Float16)a; t.h[1] = (_Float16)b; t.h[2] = (_Float16)c; t.h[3] = (_Float16)d;
    return t.u;
}
__device__ __forceinline__ unsigned umx(unsigned a, unsigned b) { return a > b ? a : b; }
#define LDS_FENCE() asm volatile("s_waitcnt lgkmcnt(0)" ::: "memory")

// ---------------- workspace layout ----------------
// float region (wsf):
//   [0..63] qw1f  [64..79] fb1 [80..95] fb2 [96..127] fb3 [128..159] fb4
//   [160..223] fbd [224..287] qwo [288] fbo   int flag @ index 290
// f16 frag region wh = (h16*)(wsf+292):
//   F2 @0 (1024), F3 @1024 (2560), F4 @3584 (5120), FD @8704 (55296)

__device__ __forceinline__ float qv(const void* src, int idx, float sc, int f32) {
    float w = ldE(src, idx, f32);
    float q = rintf(w / sc);                    // round-half-even like jnp.round
    return fminf(127.f, fmaxf(-127.f, q)) * sc; // clip then dequant
}

// Vectorized per-tensor scale: uint4 loads + integer abs-max (bit patterns of
// finite IEEE floats are magnitude-monotone after stripping sign).
__device__ float block_scale(const void* src, int n, int f32, int tid, float* red) {
    unsigned m = 0;
    const uint4* p = (const uint4*)src;
    if (f32) {
        int nv = n >> 2;
        for (int i = tid; i < nv; i += 256) {
            uint4 u = p[i];
            m = umx(m, u.x & 0x7FFFFFFFu); m = umx(m, u.y & 0x7FFFFFFFu);
            m = umx(m, u.z & 0x7FFFFFFFu); m = umx(m, u.w & 0x7FFFFFFFu);
        }
        union { unsigned u; float f; } c; c.u = m;
        red[tid] = c.f;
    } else {
        int nv = n >> 3;
        for (int i = tid; i < nv; i += 256) {
            uint4 u = p[i];
            unsigned a;
            a = u.x & 0x7FFF7FFFu; m = umx(m, a >> 16); m = umx(m, a & 0xFFFFu);
            a = u.y & 0x7FFF7FFFu; m = umx(m, a >> 16); m = umx(m, a & 0xFFFFu);
            a = u.z & 0x7FFF7FFFu; m = umx(m, a >> 16); m = umx(m, a & 0xFFFFu);
            a = u.w & 0x7FFF7FFFu; m = umx(m, a >> 16); m = umx(m, a & 0xFFFFu);
        }
        union { unsigned u; float f; } c; c.u = m << 16;
        red[tid] = c.f;
    }
    __syncthreads();
    for (int s = 128; s > 0; s >>= 1) {
        if (tid < s) red[tid] = fmaxf(red[tid], red[tid + s]);
        __syncthreads();
    }
    return red[0] / 127.f;   // exact division, matches np max|w|/127
}

// grid = 57: 0..47 FD slices, 48 qw1, 49 F2, 50..51 F3, 52..55 F4,
// 56 qwo + biases + dtype flag.
__global__ void __launch_bounds__(256) prep(
    const unsigned short* __restrict__ xu,
    const void* __restrict__ w1, const void* __restrict__ w2,
    const void* __restrict__ w3, const void* __restrict__ w4,
    const void* __restrict__ wd, const void* __restrict__ wo,
    const void* __restrict__ b1, const void* __restrict__ b2,
    const void* __restrict__ b3, const void* __restrict__ b4,
    const void* __restrict__ bd, const void* __restrict__ bo,
    float* __restrict__ wsf)
{
    int tid = threadIdx.x, which = blockIdx.x;
    __shared__ float red[256];
    __shared__ int cnt;
    if (tid == 0) cnt = 0;
    __syncthreads();
    int bad = 0;
    for (int i = tid; i < 2048; i += 256) {
        int e = (xu[i] >> 7) & 0xFF;      // bf16 exponent of x's halfwords
        if (e >= 147) bad = 1;            // |v| >= 2^20: x is not bf16 data
    }
    atomicAdd(&cnt, bad);
    __syncthreads();
    const int f32 = (cnt > 4) ? 1 : 0;
    h16* wh = (h16*)(wsf + 292);

    if (which < 48) {                     // dense frag slice (1152 elems)
        float sc = block_scale(wd, 55296, f32, tid, red);
        int e1 = (which + 1) * 1152;
        for (int e = which * 1152 + tid; e < e1; e += 256) {
            int j = e & 7, l = (e >> 3) & 63, t = e >> 9;   // t = mt*27 + c
            int mt = t / 27, c = t - mt * 27;
            int o = mt * 16 + (l & 15);
            int k = c * 32 + ((l >> 4) & 3) * 8 + j;
            int i = k >> 5, cch = k & 31;
            wh[8704 + e] = (h16)qv(wd, o * 864 + cch * 27 + i, sc, f32);
        }
    } else if (which == 48) {             // conv1 plain f32
        float sc = block_scale(w1, 64, f32, tid, red);
        if (tid < 64) wsf[tid] = qv(w1, tid, sc, f32);
    } else if (which == 49) {             // conv2 A-frags: k = dk*16+ci, pad dk=3
        float sc = block_scale(w2, 768, f32, tid, red);
        for (int e = tid; e < 1024; e += 256) {
            int c = e >> 9, l = (e >> 3) & 63, j = e & 7;
            int mm = l & 15;
            int k = c * 32 + ((l >> 4) & 3) * 8 + j;
            int dk = k >> 4, ci = k & 15;
            float v = (dk < 3) ? qv(w2, (mm * 16 + ci) * 3 + dk, sc, f32) : 0.f;
            wh[0 + e] = (h16)v;
        }
    } else if (which < 52) {              // conv3 A-frags: k = dk*16+ci, dk = chunk
        float sc = block_scale(w3, 2560, f32, tid, red);
        int e0 = (which - 50) * 1280;
        for (int e = e0 + tid; e < e0 + 1280; e += 256) {
            int c = e >> 9, l = (e >> 3) & 63, j = e & 7;
            int mm = l & 31;
            int ci = ((l >> 5) & 1) * 8 + j;
            wh[1024 + e] = (h16)qv(w3, (mm * 16 + ci) * 5 + c, sc, f32);
        }
    } else if (which < 56) {              // conv4 A-frags: k = dk*32+ci
        float sc = block_scale(w4, 5120, f32, tid, red);
        int e0 = (which - 52) * 1280;
        for (int e = e0 + tid; e < e0 + 1280; e += 256) {
            int c = e >> 9, l = (e >> 3) & 63, j = e & 7;
            int mm = l & 31;
            int k = c * 16 + ((l >> 5) & 1) * 8 + j;
            int dk = k >> 5, ci = k & 31;
            wh[3584 + e] = (h16)qv(w4, (mm * 32 + ci) * 5 + dk, sc, f32);
        }
    } else {                              // qwo + biases + flag
        float sc = block_scale(wo, 64, f32, tid, red);
        if (tid < 64) wsf[224 + tid] = qv(wo, tid, sc, f32);
        if (tid < 16)        wsf[64 + tid]        = ldE(b1, tid, f32);
        else if (tid < 32)   wsf[80 + tid - 16]   = ldE(b2, tid - 16, f32);
        else if (tid < 64)   wsf[96 + tid - 32]   = ldE(b3, tid - 32, f32);
        else if (tid < 96)   wsf[128 + tid - 64]  = ldE(b4, tid - 64, f32);
        else if (tid < 160)  wsf[160 + tid - 96]  = ldE(bd, tid - 96, f32);
        else if (tid == 160) wsf[288]             = ldE(bo, 0, f32);
        if (tid == 0) ((int*)wsf)[290] = f32;
    }
}

// Chunked activation layouts: [k-group][pos][8 h16] -> all MFMA B-fragment
// reads are lane-contiguous 16B. Biases ride in as MFMA C-init (exact f32).
__global__ void __launch_bounds__(256, 3) qcnn_main(
    const void* __restrict__ x,      // [B][2][128] bf16 or f32
    const float* __restrict__ wsf,
    void* __restrict__ out)          // [B]
{
    const int f32flag = ((const int*)wsf)[290];
    const float* qw1f = wsf;
    const float* fb1g = wsf + 64;
    const h16*  wh  = (const h16*)(wsf + 292);
    const h16*  F2g = wh;
    const h16*  F3g = wh + 1024;
    const h16*  F4g = wh + 3584;
    const h16*  FDg = wh + 8704;

    __shared__ __align__(16) h16 Uall[4][2112];
    __shared__ __align__(16) h16 Vall[4][2208];
    __shared__ __align__(16) h16 flatb[8][872];
    __shared__ float red[256];

    int tid  = threadIdx.x;
    int lane = tid & 63;
    int w    = __builtin_amdgcn_readfirstlane(tid >> 6);
    int n16  = lane & 15, kg16 = (lane >> 4) & 3;
    int n32  = lane & 31, kg32 = (lane >> 5) & 1;
    int o16  = kg16 * 4;
    h16* U = Uall[w];
    h16* V = Vall[w];
    long b0 = (long)blockIdx.x * 8;

    // loop-invariant A fragments (16B/lane coalesced)
    h16x8 a2[2], a3[5], a4[10];
#pragma unroll
    for (int c = 0; c < 2; ++c)  a2[c] = *(const h16x8*)&F2g[c * 512 + lane * 8];
#pragma unroll
    for (int c = 0; c < 5; ++c)  a3[c] = *(const h16x8*)&F3g[c * 512 + lane * 8];
#pragma unroll
    for (int c = 0; c < 10; ++c) a4[c] = *(const h16x8*)&F4g[c * 512 + lane * 8];
    f32x4 b2v = *(const f32x4*)&wsf[80 + o16];   // conv2 C-init (bias rows)
    f32x16 c3i, c4i;                             // conv3/4 C-init
#pragma unroll
    for (int g = 0; g < 4; ++g) {
        f32x4 bv3 = *(const f32x4*)&wsf[96 + 8 * g + 4 * kg32];
        f32x4 bv4 = *(const f32x4*)&wsf[128 + 8 * g + 4 * kg32];
#pragma unroll
        for (int q = 0; q < 4; ++q) { c3i[4*g+q] = bv3[q]; c4i[4*g+q] = bv4[q]; }
    }

    // hoist both samples' x loads above all LDS fences (prefetch)
    float xl[2][2][4];
#pragma unroll
    for (int it = 0; it < 2; ++it) {
        long sb = (b0 + w * 2 + it) * 256;
#pragma unroll
        for (int ci = 0; ci < 2; ++ci) {
            int rb = ci * 128;
            xl[it][ci][0] = ldE(x, sb + rb + lane, f32flag);
            xl[it][ci][1] = ldE(x, sb + rb + lane + 1, f32flag);
            xl[it][ci][2] = ldE(x, sb + rb + 64 + lane, f32flag);
            xl[it][ci][3] = ldE(x, sb + rb + 64 + ((lane + 1) & 63), f32flag);
        }
    }

    for (int it = 0; it < 2; ++it) {
        int slot = w * 2 + it;

        // ---- conv1 (VALU): -> act1 U[2g][127] ----
        LDS_FENCE();
        h16x8 ra, rbv, rc, rd;
#pragma unroll
        for (int co = 0; co < 16; ++co) {
            float w00 = qw1f[co*4+0], w01 = qw1f[co*4+1], w10 = qw1f[co*4+2], w11 = qw1f[co*4+3];
            float bb = fb1g[co];
            float v0 = bb + xl[it][0][0]*w00 + xl[it][0][1]*w01 + xl[it][1][0]*w10 + xl[it][1][1]*w11;
            float v1 = bb + xl[it][0][2]*w00 + xl[it][0][3]*w01 + xl[it][1][2]*w10 + xl[it][1][3]*w11;
            v0 = lrelu(v0); v1 = lrelu(v1);
            if (co < 8) { ra[co] = (h16)v0; rc[co] = (h16)v1; }
            else        { rbv[co-8] = (h16)v0; rd[co-8] = (h16)v1; }
        }
        *(h16x8*)&U[lane * 8]        = ra;    // g0, pos = lane
        *(h16x8*)&U[1056 + lane * 8] = rbv;   // g1
        if (lane < 63) {
            *(h16x8*)&U[(64 + lane) * 8]        = rc;
            *(h16x8*)&U[1056 + (64 + lane) * 8] = rd;
        }
        LDS_FENCE();

        // ---- conv2 (16x16x32): act1 -> act2 V[2g][125] ----
#pragma unroll
        for (int t = 0; t < 8; ++t) {
            int n = t * 16 + n16;
            f32x4 acc = b2v;                      // bias in C
#pragma unroll
            for (int c = 0; c < 2; ++c) {
                int k0 = c * 32 + kg16 * 8;
                int dk = k0 >> 4, g = (k0 & 15) >> 3;
                h16x8 bfr = *(const h16x8*)&U[g * 1056 + (n + dk) * 8];
                acc = __builtin_amdgcn_mfma_f32_16x16x32_f16(a2[c], bfr, acc, 0, 0, 0);
            }
            if (n < 125) {
                uint2 p = pack4(lrelu(acc[0]), lrelu(acc[1]), lrelu(acc[2]), lrelu(acc[3]));
                *(uint2*)&V[(o16 >> 3) * 1008 + n * 8 + (o16 & 7)] = p;
            }
        }
        LDS_FENCE();

        // ---- pool1: act2 -> pooled U[2g][62] ----
        if (lane < 62) {
#pragma unroll
            for (int g = 0; g < 2; ++g) {
                h16x8 pa = *(const h16x8*)&V[g * 1008 + (2 * lane) * 8];
                h16x8 pb = *(const h16x8*)&V[g * 1008 + (2 * lane + 1) * 8];
                h16x8 mm;
#pragma unroll
                for (int e = 0; e < 8; ++e) mm[e] = pa[e] > pb[e] ? pa[e] : pb[e];
                *(h16x8*)&U[g * 1056 + lane * 8] = mm;
            }
        }
        LDS_FENCE();

        // ---- conv3 (32x32x16): pooled -> act3 V[4g][58] ----
#pragma unroll
        for (int t = 0; t < 2; ++t) {
            int n = t * 32 + n32;
            f32x16 acc = c3i;                     // bias in C
#pragma unroll
            for (int c = 0; c < 5; ++c) {
                h16x8 bfr = *(const h16x8*)&U[kg32 * 1056 + (n + c) * 8];
                acc = __builtin_amdgcn_mfma_f32_32x32x16_f16(a3[c], bfr, acc, 0, 0, 0);
            }
            if (n < 58) {
#pragma unroll
                for (int g = 0; g < 4; ++g) {
                    uint2 p = pack4(lrelu(acc[4*g+0]), lrelu(acc[4*g+1]),
                                    lrelu(acc[4*g+2]), lrelu(acc[4*g+3]));
                    *(uint2*)&V[g * 552 + n * 8 + 4 * kg32] = p;
                }
            }
        }
        LDS_FENCE();

        // ---- conv4 (32x32x16): act3 -> act4 U[4g][54] ----
#pragma unroll
        for (int t = 0; t < 2; ++t) {
            int n = t * 32 + n32;
            f32x16 acc = c4i;                     // bias in C
#pragma unroll
            for (int c = 0; c < 10; ++c) {
                int k0 = c * 16 + kg32 * 8;
                int dk = k0 >> 5, g = (k0 >> 3) & 3;
                h16x8 bfr = *(const h16x8*)&V[g * 552 + (n + dk) * 8];
                acc = __builtin_amdgcn_mfma_f32_32x32x16_f16(a4[c], bfr, acc, 0, 0, 0);
            }
            if (n < 54) {
#pragma unroll
                for (int g = 0; g < 4; ++g) {
                    uint2 p = pack4(lrelu(acc[4*g+0]), lrelu(acc[4*g+1]),
                                    lrelu(acc[4*g+2]), lrelu(acc[4*g+3]));
                    *(uint2*)&U[g * 448 + n * 8 + 4 * kg32] = p;
                }
            }
        }
        LDS_FENCE();

        // ---- pool2 + flatten: act4 -> flatb[slot], phys chunk = g*27 + pos ----
        if (lane < 27) {
#pragma unroll
            for (int g = 0; g < 4; ++g) {
                h16x8 pa = *(const h16x8*)&U[g * 448 + (2 * lane) * 8];
                h16x8 pb = *(const h16x8*)&U[g * 448 + (2 * lane + 1) * 8];
                h16x8 mm;
#pragma unroll
                for (int e = 0; e < 8; ++e) mm[e] = pa[e] > pb[e] ? pa[e] : pb[e];
                *(h16x8*)&flatb[slot][(g * 27 + lane) * 8] = mm;
            }
        }
    }
    __syncthreads();

    // ---- dense (16x16x32): flatb[8][864] @ FD, wave w = m-tile ----
    int o0g = w * 16 + o16;
    f32x4 dacc = *(const f32x4*)&wsf[160 + o0g];  // bias in C
    for (int c = 0; c < 27; ++c) {
        h16x8 aw = *(const h16x8*)&FDg[((w * 27 + c) * 64 + lane) * 8];
        h16x8 bh = *(const h16x8*)&flatb[lane & 7][(kg16 * 27 + c) * 8];
        dacc = __builtin_amdgcn_mfma_f32_16x16x32_f16(aw, bh, dacc, 0, 0, 0);
    }
    f32x4 qov = *(const f32x4*)&wsf[224 + o0g];
    float part = 0.f;
#pragma unroll
    for (int q = 0; q < 4; ++q) part += lrelu(dacc[q]) * qov[q];
    red[tid] = part;
    __syncthreads();
    if (tid < 8) {
        float y = wsf[288];
#pragma unroll
        for (int g = 0; g < 16; ++g) y += red[(g >> 2) * 64 + (g & 3) * 16 + tid];
        if (f32flag) ((float*)out)[b0 + tid] = y;
        else         ((bf16*)out)[b0 + tid] = __float2bfloat16(y);
    }
}

extern "C" void kernel_launch(void* const* d_in, const int* in_sizes, int n_in,
                              void* d_out, int out_size, void* d_ws, size_t ws_size,
                              hipStream_t stream) {
    const void* x  = d_in[0];
    const void* w1 = d_in[1];
    const void* b1 = d_in[2];
    const void* w2 = d_in[3];
    const void* b2 = d_in[4];
    const void* w3 = d_in[5];
    const void* b3 = d_in[6];
    const void* w4 = d_in[7];
    const void* b4 = d_in[8];
    const void* wd = d_in[9];
    const void* bd = d_in[10];
    const void* wo = d_in[11];
    const void* bo = d_in[12];
    float* wsf = (float*)d_ws;

    int B = in_sizes[0] / 256;            // 32768
    prep<<<57, 256, 0, stream>>>((const unsigned short*)x,
                                 w1, w2, w3, w4, wd, wo,
                                 b1, b2, b3, b4, bd, bo, wsf);
    qcnn_main<<<B / 8, 256, 0, stream>>>(x, wsf, d_out);
}

// Round 6
// 199.999 us; speedup vs baseline: 1.0746x; 1.0746x over previous
//
#include <hip/hip_runtime.h>
#include <hip/hip_bf16.h>

typedef __hip_bfloat16 bf16;
typedef _Float16 h16;
typedef __attribute__((ext_vector_type(8))) _Float16 h16x8;
typedef __attribute__((ext_vector_type(4))) float f32x4;
typedef __attribute__((ext_vector_type(16))) float f32x16;

__device__ __forceinline__ float lrelu(float x) { return fmaxf(x, 0.1f * x); }
__device__ __forceinline__ float ldE(const void* p, long i, int f32) {
    return f32 ? ((const float*)p)[i] : __bfloat162float(((const bf16*)p)[i]);
}
__device__ __forceinline__ uint2 pack4(float a, float b, float c, float d) {
    union { _Float16 h[4]; uint2 u; } t;
    t.h[0] = (_Float16)a; t.h[1] = (_Float16)b; t.h[2] = (_Float16)c; t.h[3] = (_Float16)d;
    return t.u;
}
__device__ __forceinline__ unsigned umx(unsigned a, unsigned b) { return a > b ? a : b; }
#define LDS_FENCE() asm volatile("s_waitcnt lgkmcnt(0)" ::: "memory")

// ---------------- workspace layout ----------------
// float region (wsf):
//   [64..79] fb1 [80..95] fb2 [96..127] fb3 [128..159] fb4
//   [160..223] fbd [224..287] qwo [288] fbo   int flag @ index 290
// f16 frag region wh = (h16*)(wsf+292):
//   F2 @0 (1024), F3 @1024 (2560), F4 @3584 (5120), FD @8704 (55296),
//   F1 @64000 (512)   (conv1 16x16x32 frags, k = dk*8+ci, K pad 4->32)

__device__ __forceinline__ float qv(const void* src, int idx, float sc, int f32) {
    float w = ldE(src, idx, f32);
    float q = rintf(w / sc);                    // round-half-even like jnp.round
    return fminf(127.f, fmaxf(-127.f, q)) * sc; // clip then dequant
}

// Vectorized per-tensor scale: uint4 loads + integer abs-max (bit patterns of
// finite IEEE floats are magnitude-monotone after stripping sign).
__device__ float block_scale(const void* src, int n, int f32, int tid, float* red) {
    unsigned m = 0;
    const uint4* p = (const uint4*)src;
    if (f32) {
        int nv = n >> 2;
        for (int i = tid; i < nv; i += 256) {
            uint4 u = p[i];
            m = umx(m, u.x & 0x7FFFFFFFu); m = umx(m, u.y & 0x7FFFFFFFu);
            m = umx(m, u.z & 0x7FFFFFFFu); m = umx(m, u.w & 0x7FFFFFFFu);
        }
        union { unsigned u; float f; } c; c.u = m;
        red[tid] = c.f;
    } else {
        int nv = n >> 3;
        for (int i = tid; i < nv; i += 256) {
            uint4 u = p[i];
            unsigned a;
            a = u.x & 0x7FFF7FFFu; m = umx(m, a >> 16); m = umx(m, a & 0xFFFFu);
            a = u.y & 0x7FFF7FFFu; m = umx(m, a >> 16); m = umx(m, a & 0xFFFFu);
            a = u.z & 0x7FFF7FFFu; m = umx(m, a >> 16); m = umx(m, a & 0xFFFFu);
            a = u.w & 0x7FFF7FFFu; m = umx(m, a >> 16); m = umx(m, a & 0xFFFFu);
        }
        union { unsigned u; float f; } c; c.u = m << 16;
        red[tid] = c.f;
    }
    __syncthreads();
    for (int s = 128; s > 0; s >>= 1) {
        if (tid < s) red[tid] = fmaxf(red[tid], red[tid + s]);
        __syncthreads();
    }
    return red[0] / 127.f;   // exact division, matches np max|w|/127
}

// grid = 57: 0..47 FD slices, 48 F1, 49 F2, 50..51 F3, 52..55 F4,
// 56 qwo + biases + dtype flag.
__global__ void __launch_bounds__(256) prep(
    const unsigned short* __restrict__ xu,
    const void* __restrict__ w1, const void* __restrict__ w2,
    const void* __restrict__ w3, const void* __restrict__ w4,
    const void* __restrict__ wd, const void* __restrict__ wo,
    const void* __restrict__ b1, const void* __restrict__ b2,
    const void* __restrict__ b3, const void* __restrict__ b4,
    const void* __restrict__ bd, const void* __restrict__ bo,
    float* __restrict__ wsf)
{
    int tid = threadIdx.x, which = blockIdx.x;
    __shared__ float red[256];
    __shared__ int cnt;
    if (tid == 0) cnt = 0;
    __syncthreads();
    int bad = 0;
    for (int i = tid; i < 2048; i += 256) {
        int e = (xu[i] >> 7) & 0xFF;      // bf16 exponent of x's halfwords
        if (e >= 147) bad = 1;            // |v| >= 2^20: x is not bf16 data
    }
    atomicAdd(&cnt, bad);
    __syncthreads();
    const int f32 = (cnt > 4) ? 1 : 0;
    h16* wh = (h16*)(wsf + 292);

    if (which < 48) {                     // dense frag slice (1152 elems)
        float sc = block_scale(wd, 55296, f32, tid, red);
        int e1 = (which + 1) * 1152;
        for (int e = which * 1152 + tid; e < e1; e += 256) {
            int j = e & 7, l = (e >> 3) & 63, t = e >> 9;   // t = mt*27 + c
            int mt = t / 27, c = t - mt * 27;
            int o = mt * 16 + (l & 15);
            int k = c * 32 + ((l >> 4) & 3) * 8 + j;
            int i = k >> 5, cch = k & 31;
            wh[8704 + e] = (h16)qv(wd, o * 864 + cch * 27 + i, sc, f32);
        }
    } else if (which == 48) {             // conv1 A-frags: k = dk*8+ci, real k: dk<2,ci<2
        float sc = block_scale(w1, 64, f32, tid, red);
        for (int e = tid; e < 512; e += 256) {
            int l = e >> 3, j = e & 7;
            int co = l & 15, kg = (l >> 4) & 3;     // dk = kg, ci = j
            float v = (kg < 2 && j < 2) ? qv(w1, co * 4 + j * 2 + kg, sc, f32) : 0.f;
            wh[64000 + e] = (h16)v;
        }
    } else if (which == 49) {             // conv2 A-frags: k = dk*16+ci, pad dk=3
        float sc = block_scale(w2, 768, f32, tid, red);
        for (int e = tid; e < 1024; e += 256) {
            int c = e >> 9, l = (e >> 3) & 63, j = e & 7;
            int mm = l & 15;
            int k = c * 32 + ((l >> 4) & 3) * 8 + j;
            int dk = k >> 4, ci = k & 15;
            float v = (dk < 3) ? qv(w2, (mm * 16 + ci) * 3 + dk, sc, f32) : 0.f;
            wh[0 + e] = (h16)v;
        }
    } else if (which < 52) {              // conv3 A-frags: k = dk*16+ci, dk = chunk
        float sc = block_scale(w3, 2560, f32, tid, red);
        int e0 = (which - 50) * 1280;
        for (int e = e0 + tid; e < e0 + 1280; e += 256) {
            int c = e >> 9, l = (e >> 3) & 63, j = e & 7;
            int mm = l & 31;
            int ci = ((l >> 5) & 1) * 8 + j;
            wh[1024 + e] = (h16)qv(w3, (mm * 16 + ci) * 5 + c, sc, f32);
        }
    } else if (which < 56) {              // conv4 A-frags: k = dk*32+ci
        float sc = block_scale(w4, 5120, f32, tid, red);
        int e0 = (which - 52) * 1280;
        for (int e = e0 + tid; e < e0 + 1280; e += 256) {
            int c = e >> 9, l = (e >> 3) & 63, j = e & 7;
            int mm = l & 31;
            int k = c * 16 + ((l >> 5) & 1) * 8 + j;
            int dk = k >> 5, ci = k & 31;
            wh[3584 + e] = (h16)qv(w4, (mm * 32 + ci) * 5 + dk, sc, f32);
        }
    } else {                              // qwo + biases + flag
        float sc = block_scale(wo, 64, f32, tid, red);
        if (tid < 64) wsf[224 + tid] = qv(wo, tid, sc, f32);
        if (tid < 16)        wsf[64 + tid]        = ldE(b1, tid, f32);
        else if (tid < 32)   wsf[80 + tid - 16]   = ldE(b2, tid - 16, f32);
        else if (tid < 64)   wsf[96 + tid - 32]   = ldE(b3, tid - 32, f32);
        else if (tid < 96)   wsf[128 + tid - 64]  = ldE(b4, tid - 64, f32);
        else if (tid < 160)  wsf[160 + tid - 96]  = ldE(bd, tid - 96, f32);
        else if (tid == 160) wsf[288]             = ldE(bo, 0, f32);
        if (tid == 0) ((int*)wsf)[290] = f32;
    }
}

// All convs on MFMA with chunked [k-group][pos][8 h16] LDS layouts: every
// B-fragment read is one lane-contiguous 16B ds_read_b128 (no conflicts).
__global__ void __launch_bounds__(256, 3) qcnn_main(
    const void* __restrict__ x,      // [B][2][128] bf16 or f32
    const float* __restrict__ wsf,
    void* __restrict__ out)          // [B]
{
    const int f32flag = ((const int*)wsf)[290];
    const h16*  wh  = (const h16*)(wsf + 292);
    const h16*  F2g = wh;
    const h16*  F3g = wh + 1024;
    const h16*  F4g = wh + 3584;
    const h16*  FDg = wh + 8704;
    const h16*  F1g = wh + 64000;

    __shared__ __align__(16) h16 Uall[4][2112];
    __shared__ __align__(16) h16 Vall[4][2208];
    __shared__ __align__(16) h16 flatb[8][872];
    __shared__ float red[256];

    int tid  = threadIdx.x;
    int lane = tid & 63;
    int w    = __builtin_amdgcn_readfirstlane(tid >> 6);
    int n16  = lane & 15, kg16 = (lane >> 4) & 3;
    int n32  = lane & 31, kg32 = (lane >> 5) & 1;
    int o16  = kg16 * 4;
    h16* U = Uall[w];
    h16* V = Vall[w];
    long b0 = (long)blockIdx.x * 8;

    // loop-invariant A fragments (16B/lane coalesced)
    h16x8 a1, a2[2], a3[5], a4[10];
    a1 = *(const h16x8*)&F1g[lane * 8];
#pragma unroll
    for (int c = 0; c < 2; ++c)  a2[c] = *(const h16x8*)&F2g[c * 512 + lane * 8];
#pragma unroll
    for (int c = 0; c < 5; ++c)  a3[c] = *(const h16x8*)&F3g[c * 512 + lane * 8];
#pragma unroll
    for (int c = 0; c < 10; ++c) a4[c] = *(const h16x8*)&F4g[c * 512 + lane * 8];
    f32x4 b1v = *(const f32x4*)&wsf[64 + o16];   // conv1 C-init
    f32x4 b2v = *(const f32x4*)&wsf[80 + o16];   // conv2 C-init

    const h16 hz = (h16)0.f;
    const h16x8 zrow = {hz, hz, hz, hz, hz, hz, hz, hz};

    for (int it = 0; it < 2; ++it) {
        int slot = w * 2 + it;
        long sb = (b0 + slot) * 256;

        // ---- stage x as xi8 rows in V: row p = {x0[p], x1[p], 0...} ----
        LDS_FENCE();   // prev iteration's V readers (conv4) done
        {
            float x00 = ldE(x, sb + lane, f32flag);         // ch0, p = lane
            float x10 = ldE(x, sb + 128 + lane, f32flag);   // ch1
            float x01 = ldE(x, sb + 64 + lane, f32flag);    // ch0, p = 64+lane
            float x11 = ldE(x, sb + 192 + lane, f32flag);
            h16x8 r0 = zrow, r1 = zrow;
            r0[0] = (h16)x00; r0[1] = (h16)x10;
            r1[0] = (h16)x01; r1[1] = (h16)x11;
            *(h16x8*)&V[lane * 8]        = r0;
            *(h16x8*)&V[(64 + lane) * 8] = r1;
            if (lane < 3) *(h16x8*)&V[(128 + lane) * 8] = zrow;  // pad rows 128..130
        }
        LDS_FENCE();

        // ---- conv1 (16x16x32, K pad 4->32): xi8 -> act1 U[2g][127] ----
#pragma unroll
        for (int t = 0; t < 8; ++t) {
            int n = t * 16 + n16;
            f32x4 acc = b1v;
            h16x8 bfr = *(const h16x8*)&V[(n + kg16) * 8];
            acc = __builtin_amdgcn_mfma_f32_16x16x32_f16(a1, bfr, acc, 0, 0, 0);
            if (n < 127) {
                uint2 p = pack4(lrelu(acc[0]), lrelu(acc[1]), lrelu(acc[2]), lrelu(acc[3]));
                *(uint2*)&V[0];  // no-op guard (kept simple)
                *(uint2*)&U[(o16 >> 3) * 1056 + n * 8 + (o16 & 7)] = p;
            }
        }
        // zero act1 pad rows 127..130 (both groups) so conv2's zero-A columns
        // never touch stale/NaN LDS
        if (lane < 8) {
            int g = lane & 1, row = 127 + (lane >> 1);
            *(uint4*)&U[g * 1056 + row * 8] = make_uint4(0, 0, 0, 0);
        }
        LDS_FENCE();

        // ---- conv2 (16x16x32): act1 -> act2 V[2g][125] ----
#pragma unroll
        for (int t = 0; t < 8; ++t) {
            int n = t * 16 + n16;
            f32x4 acc = b2v;
#pragma unroll
            for (int c = 0; c < 2; ++c) {
                int k0 = c * 32 + kg16 * 8;
                int dk = k0 >> 4, g = (k0 & 15) >> 3;
                h16x8 bfr = *(const h16x8*)&U[g * 1056 + (n + dk) * 8];
                acc = __builtin_amdgcn_mfma_f32_16x16x32_f16(a2[c], bfr, acc, 0, 0, 0);
            }
            if (n < 125) {
                uint2 p = pack4(lrelu(acc[0]), lrelu(acc[1]), lrelu(acc[2]), lrelu(acc[3]));
                *(uint2*)&V[(o16 >> 3) * 1008 + n * 8 + (o16 & 7)] = p;
            }
        }
        LDS_FENCE();

        // ---- pool1: act2 -> pooled U[2g][62] ----
        if (lane < 62) {
#pragma unroll
            for (int g = 0; g < 2; ++g) {
                h16x8 pa = *(const h16x8*)&V[g * 1008 + (2 * lane) * 8];
                h16x8 pb = *(const h16x8*)&V[g * 1008 + (2 * lane + 1) * 8];
                h16x8 mm;
#pragma unroll
                for (int e = 0; e < 8; ++e) mm[e] = pa[e] > pb[e] ? pa[e] : pb[e];
                *(h16x8*)&U[g * 1056 + lane * 8] = mm;
            }
        }
        LDS_FENCE();

        // ---- conv3 (32x32x16): pooled -> act3 V[4g][58] ----
#pragma unroll
        for (int t = 0; t < 2; ++t) {
            int n = t * 32 + n32;
            f32x16 acc = {0.f,0.f,0.f,0.f,0.f,0.f,0.f,0.f,0.f,0.f,0.f,0.f,0.f,0.f,0.f,0.f};
#pragma unroll
            for (int c = 0; c < 5; ++c) {
                h16x8 bfr = *(const h16x8*)&U[kg32 * 1056 + (n + c) * 8];
                acc = __builtin_amdgcn_mfma_f32_32x32x16_f16(a3[c], bfr, acc, 0, 0, 0);
            }
            if (n < 58) {
#pragma unroll
                for (int g = 0; g < 4; ++g) {
                    int r0 = 8 * g + 4 * kg32;
                    f32x4 bv = *(const f32x4*)&wsf[96 + r0];
                    uint2 p = pack4(lrelu(acc[4*g+0] + bv[0]), lrelu(acc[4*g+1] + bv[1]),
                                    lrelu(acc[4*g+2] + bv[2]), lrelu(acc[4*g+3] + bv[3]));
                    *(uint2*)&V[g * 552 + n * 8 + 4 * kg32] = p;
                }
            }
        }
        LDS_FENCE();

        // ---- conv4 (32x32x16): act3 -> act4 U[4g][54] ----
#pragma unroll
        for (int t = 0; t < 2; ++t) {
            int n = t * 32 + n32;
            f32x16 acc = {0.f,0.f,0.f,0.f,0.f,0.f,0.f,0.f,0.f,0.f,0.f,0.f,0.f,0.f,0.f,0.f};
#pragma unroll
            for (int c = 0; c < 10; ++c) {
                int k0 = c * 16 + kg32 * 8;
                int dk = k0 >> 5, g = (k0 >> 3) & 3;
                h16x8 bfr = *(const h16x8*)&V[g * 552 + (n + dk) * 8];
                acc = __builtin_amdgcn_mfma_f32_32x32x16_f16(a4[c], bfr, acc, 0, 0, 0);
            }
            if (n < 54) {
#pragma unroll
                for (int g = 0; g < 4; ++g) {
                    int r0 = 8 * g + 4 * kg32;
                    f32x4 bv = *(const f32x4*)&wsf[128 + r0];
                    uint2 p = pack4(lrelu(acc[4*g+0] + bv[0]), lrelu(acc[4*g+1] + bv[1]),
                                    lrelu(acc[4*g+2] + bv[2]), lrelu(acc[4*g+3] + bv[3]));
                    *(uint2*)&U[g * 448 + n * 8 + 4 * kg32] = p;
                }
            }
        }
        LDS_FENCE();

        // ---- pool2 + flatten: act4 -> flatb[slot], phys chunk = g*27 + pos ----
        if (lane < 27) {
#pragma unroll
            for (int g = 0; g < 4; ++g) {
                h16x8 pa = *(const h16x8*)&U[g * 448 + (2 * lane) * 8];
                h16x8 pb = *(const h16x8*)&U[g * 448 + (2 * lane + 1) * 8];
                h16x8 mm;
#pragma unroll
                for (int e = 0; e < 8; ++e) mm[e] = pa[e] > pb[e] ? pa[e] : pb[e];
                *(h16x8*)&flatb[slot][(g * 27 + lane) * 8] = mm;
            }
        }
    }
    __syncthreads();

    // ---- dense (16x16x32): flatb[8][864] @ FD, wave w = m-tile ----
    int o0g = w * 16 + o16;
    f32x4 dacc = *(const f32x4*)&wsf[160 + o0g];  // bias in C
    for (int c = 0; c < 27; ++c) {
        h16x8 aw = *(const h16x8*)&FDg[((w * 27 + c) * 64 + lane) * 8];
        h16x8 bh = *(const h16x8*)&flatb[lane & 7][(kg16 * 27 + c) * 8];
        dacc = __builtin_amdgcn_mfma_f32_16x16x32_f16(aw, bh, dacc, 0, 0, 0);
    }
    f32x4 qov = *(const f32x4*)&wsf[224 + o0g];
    float part = 0.f;
#pragma unroll
    for (int q = 0; q < 4; ++q) part += lrelu(dacc[q]) * qov[q];
    red[tid] = part;
    __syncthreads();
    if (tid < 8) {
        float y = wsf[288];
#pragma unroll
        for (int g = 0; g < 16; ++g) y += red[(g >> 2) * 64 + (g & 3) * 16 + tid];
        if (f32flag) ((float*)out)[b0 + tid] = y;
        else         ((bf16*)out)[b0 + tid] = __float2bfloat16(y);
    }
}

extern "C" void kernel_launch(void* const* d_in, const int* in_sizes, int n_in,
                              void* d_out, int out_size, void* d_ws, size_t ws_size,
                              hipStream_t stream) {
    const void* x  = d_in[0];
    const void* w1 = d_in[1];
    const void* b1 = d_in[2];
    const void* w2 = d_in[3];
    const void* b2 = d_in[4];
    const void* w3 = d_in[5];
    const void* b3 = d_in[6];
    const void* w4 = d_in[7];
    const void* b4 = d_in[8];
    const void* wd = d_in[9];
    const void* bd = d_in[10];
    const void* wo = d_in[11];
    const void* bo = d_in[12];
    float* wsf = (float*)d_ws;

    int B = in_sizes[0] / 256;            // 32768
    prep<<<57, 256, 0, stream>>>((const unsigned short*)x,
                                 w1, w2, w3, w4, wd, wo,
                                 b1, b2, b3, b4, bd, bo, wsf);
    qcnn_main<<<B / 8, 256, 0, stream>>>(x, wsf, d_out);
}

// Round 7
// 196.480 us; speedup vs baseline: 1.0939x; 1.0179x over previous
//
#include <hip/hip_runtime.h>
#include <hip/hip_bf16.h>

typedef __hip_bfloat16 bf16;
typedef _Float16 h16;
typedef __attribute__((ext_vector_type(8))) _Float16 h16x8;
typedef __attribute__((ext_vector_type(4))) float f32x4;
typedef __attribute__((ext_vector_type(16))) float f32x16;

__device__ __forceinline__ float lrelu(float x) { return fmaxf(x, 0.1f * x); }
__device__ __forceinline__ float ldE(const void* p, long i, int f32) {
    return f32 ? ((const float*)p)[i] : __bfloat162float(((const bf16*)p)[i]);
}
__device__ __forceinline__ uint2 pack4(float a, float b, float c, float d) {
    union { _Float16 h[4]; uint2 u; } t;
    t.h[0] = (_Float16)a; t.h[1] = (_Float16)b; t.h[2] = (_Float16)c; t.h[3] = (_Float16)d;
    return t.u;
}
__device__ __forceinline__ unsigned umx(unsigned a, unsigned b) { return a > b ? a : b; }
#define LDS_FENCE() asm volatile("s_waitcnt lgkmcnt(0)" ::: "memory")

// ---------------- workspace layout ----------------
// float region (wsf):
//   [64..79] fb1 [80..95] fb2 [96..127] fb3 [128..159] fb4
//   [160..223] fbd [224..287] qwo [288] fbo   int flag @ index 290
// f16 frag region wh = (h16*)(wsf+292):
//   F2 @0 (1024), F3 @1024 (2560), F4 @3584 (5120), FD @8704 (55296),
//   F1 @64000 (512)   (conv1 16x16x32 frags, k = dk*8+ci, K pad 4->32)

__device__ __forceinline__ float qv(const void* src, int idx, float sc, int f32) {
    float w = ldE(src, idx, f32);
    float q = rintf(w / sc);                    // round-half-even like jnp.round
    return fminf(127.f, fmaxf(-127.f, q)) * sc; // clip then dequant
}

// Vectorized per-tensor scale: uint4 loads + integer abs-max (bit patterns of
// finite IEEE floats are magnitude-monotone after stripping sign).
__device__ float block_scale(const void* src, int n, int f32, int tid, float* red) {
    unsigned m = 0;
    const uint4* p = (const uint4*)src;
    if (f32) {
        int nv = n >> 2;
        for (int i = tid; i < nv; i += 256) {
            uint4 u = p[i];
            m = umx(m, u.x & 0x7FFFFFFFu); m = umx(m, u.y & 0x7FFFFFFFu);
            m = umx(m, u.z & 0x7FFFFFFFu); m = umx(m, u.w & 0x7FFFFFFFu);
        }
        union { unsigned u; float f; } c; c.u = m;
        red[tid] = c.f;
    } else {
        int nv = n >> 3;
        for (int i = tid; i < nv; i += 256) {
            uint4 u = p[i];
            unsigned a;
            a = u.x & 0x7FFF7FFFu; m = umx(m, a >> 16); m = umx(m, a & 0xFFFFu);
            a = u.y & 0x7FFF7FFFu; m = umx(m, a >> 16); m = umx(m, a & 0xFFFFu);
            a = u.z & 0x7FFF7FFFu; m = umx(m, a >> 16); m = umx(m, a & 0xFFFFu);
            a = u.w & 0x7FFF7FFFu; m = umx(m, a >> 16); m = umx(m, a & 0xFFFFu);
        }
        union { unsigned u; float f; } c; c.u = m << 16;
        red[tid] = c.f;
    }
    __syncthreads();
    for (int s = 128; s > 0; s >>= 1) {
        if (tid < s) red[tid] = fmaxf(red[tid], red[tid + s]);
        __syncthreads();
    }
    return red[0] / 127.f;   // exact division, matches np max|w|/127
}

// grid = 57: 0..47 FD slices, 48 F1, 49 F2, 50..51 F3, 52..55 F4,
// 56 qwo + biases + dtype flag.
__global__ void __launch_bounds__(256) prep(
    const unsigned short* __restrict__ xu,
    const void* __restrict__ w1, const void* __restrict__ w2,
    const void* __restrict__ w3, const void* __restrict__ w4,
    const void* __restrict__ wd, const void* __restrict__ wo,
    const void* __restrict__ b1, const void* __restrict__ b2,
    const void* __restrict__ b3, const void* __restrict__ b4,
    const void* __restrict__ bd, const void* __restrict__ bo,
    float* __restrict__ wsf)
{
    int tid = threadIdx.x, which = blockIdx.x;
    __shared__ float red[256];
    __shared__ int cnt;
    if (tid == 0) cnt = 0;
    __syncthreads();
    int bad = 0;
    for (int i = tid; i < 2048; i += 256) {
        int e = (xu[i] >> 7) & 0xFF;      // bf16 exponent of x's halfwords
        if (e >= 147) bad = 1;            // |v| >= 2^20: x is not bf16 data
    }
    atomicAdd(&cnt, bad);
    __syncthreads();
    const int f32 = (cnt > 4) ? 1 : 0;
    h16* wh = (h16*)(wsf + 292);

    if (which < 48) {                     // dense frag slice (1152 elems)
        float sc = block_scale(wd, 55296, f32, tid, red);
        int e1 = (which + 1) * 1152;
        for (int e = which * 1152 + tid; e < e1; e += 256) {
            int j = e & 7, l = (e >> 3) & 63, t = e >> 9;   // t = mt*27 + c
            int mt = t / 27, c = t - mt * 27;
            int o = mt * 16 + (l & 15);
            int k = c * 32 + ((l >> 4) & 3) * 8 + j;
            int i = k >> 5, cch = k & 31;
            wh[8704 + e] = (h16)qv(wd, o * 864 + cch * 27 + i, sc, f32);
        }
    } else if (which == 48) {             // conv1 A-frags: k = dk*8+ci, real k: dk<2,ci<2
        float sc = block_scale(w1, 64, f32, tid, red);
        for (int e = tid; e < 512; e += 256) {
            int l = e >> 3, j = e & 7;
            int co = l & 15, kg = (l >> 4) & 3;     // dk = kg, ci = j
            float v = (kg < 2 && j < 2) ? qv(w1, co * 4 + j * 2 + kg, sc, f32) : 0.f;
            wh[64000 + e] = (h16)v;
        }
    } else if (which == 49) {             // conv2 A-frags: k = dk*16+ci, pad dk=3
        float sc = block_scale(w2, 768, f32, tid, red);
        for (int e = tid; e < 1024; e += 256) {
            int c = e >> 9, l = (e >> 3) & 63, j = e & 7;
            int mm = l & 15;
            int k = c * 32 + ((l >> 4) & 3) * 8 + j;
            int dk = k >> 4, ci = k & 15;
            float v = (dk < 3) ? qv(w2, (mm * 16 + ci) * 3 + dk, sc, f32) : 0.f;
            wh[0 + e] = (h16)v;
        }
    } else if (which < 52) {              // conv3 A-frags: k = dk*16+ci, dk = chunk
        float sc = block_scale(w3, 2560, f32, tid, red);
        int e0 = (which - 50) * 1280;
        for (int e = e0 + tid; e < e0 + 1280; e += 256) {
            int c = e >> 9, l = (e >> 3) & 63, j = e & 7;
            int mm = l & 31;
            int ci = ((l >> 5) & 1) * 8 + j;
            wh[1024 + e] = (h16)qv(w3, (mm * 16 + ci) * 5 + c, sc, f32);
        }
    } else if (which < 56) {              // conv4 A-frags: k = dk*32+ci
        float sc = block_scale(w4, 5120, f32, tid, red);
        int e0 = (which - 52) * 1280;
        for (int e = e0 + tid; e < e0 + 1280; e += 256) {
            int c = e >> 9, l = (e >> 3) & 63, j = e & 7;
            int mm = l & 31;
            int k = c * 16 + ((l >> 5) & 1) * 8 + j;
            int dk = k >> 5, ci = k & 31;
            wh[3584 + e] = (h16)qv(w4, (mm * 32 + ci) * 5 + dk, sc, f32);
        }
    } else {                              // qwo + biases + flag
        float sc = block_scale(wo, 64, f32, tid, red);
        if (tid < 64) wsf[224 + tid] = qv(wo, tid, sc, f32);
        if (tid < 16)        wsf[64 + tid]        = ldE(b1, tid, f32);
        else if (tid < 32)   wsf[80 + tid - 16]   = ldE(b2, tid - 16, f32);
        else if (tid < 64)   wsf[96 + tid - 32]   = ldE(b3, tid - 32, f32);
        else if (tid < 96)   wsf[128 + tid - 64]  = ldE(b4, tid - 64, f32);
        else if (tid < 160)  wsf[160 + tid - 96]  = ldE(bd, tid - 96, f32);
        else if (tid == 160) wsf[288]             = ldE(bo, 0, f32);
        if (tid == 0) ((int*)wsf)[290] = f32;
    }
}

// All convs on MFMA with chunked [k-group][pos][8 h16] LDS layouts: every
// B-fragment read is one lane-contiguous 16B ds_read_b128 (no conflicts).
// launch_bounds(256,2): cap 256 VGPR -> no scratch spill (84-cap at min=3
// spilled ~14B/thread, round 5/6 WRITE_SIZE evidence); allocator demand
// ~130-170 still fits 3 waves/SIMD in HW.
__global__ void __launch_bounds__(256, 2) qcnn_main(
    const void* __restrict__ x,      // [B][2][128] bf16 or f32
    const float* __restrict__ wsf,
    void* __restrict__ out)          // [B]
{
    const int f32flag = ((const int*)wsf)[290];
    const h16*  wh  = (const h16*)(wsf + 292);
    const h16*  F2g = wh;
    const h16*  F3g = wh + 1024;
    const h16*  F4g = wh + 3584;
    const h16*  FDg = wh + 8704;
    const h16*  F1g = wh + 64000;

    __shared__ __align__(16) h16 Uall[4][2112];
    __shared__ __align__(16) h16 Vall[4][2208];
    __shared__ __align__(16) h16 flatb[8][872];
    __shared__ float red[256];

    int tid  = threadIdx.x;
    int lane = tid & 63;
    int w    = __builtin_amdgcn_readfirstlane(tid >> 6);
    int n16  = lane & 15, kg16 = (lane >> 4) & 3;
    int n32  = lane & 31, kg32 = (lane >> 5) & 1;
    int o16  = kg16 * 4;
    h16* U = Uall[w];
    h16* V = Vall[w];
    long b0 = (long)blockIdx.x * 8;

    // loop-invariant A fragments (16B/lane coalesced)
    h16x8 a1, a2[2], a3[5], a4[10];
    a1 = *(const h16x8*)&F1g[lane * 8];
#pragma unroll
    for (int c = 0; c < 2; ++c)  a2[c] = *(const h16x8*)&F2g[c * 512 + lane * 8];
#pragma unroll
    for (int c = 0; c < 5; ++c)  a3[c] = *(const h16x8*)&F3g[c * 512 + lane * 8];
#pragma unroll
    for (int c = 0; c < 10; ++c) a4[c] = *(const h16x8*)&F4g[c * 512 + lane * 8];
    f32x4 b1v = *(const f32x4*)&wsf[64 + o16];   // conv1 C-init
    f32x4 b2v = *(const f32x4*)&wsf[80 + o16];   // conv2 C-init

    const h16 hz = (h16)0.f;
    const h16x8 zrow = {hz, hz, hz, hz, hz, hz, hz, hz};

    for (int it = 0; it < 2; ++it) {
        int slot = w * 2 + it;
        long sb = (b0 + slot) * 256;

        // ---- stage x as xi8 rows in V: row p = {x0[p], x1[p], 0...} ----
        LDS_FENCE();   // prev iteration's V readers (conv4) done
        {
            float x00 = ldE(x, sb + lane, f32flag);         // ch0, p = lane
            float x10 = ldE(x, sb + 128 + lane, f32flag);   // ch1
            float x01 = ldE(x, sb + 64 + lane, f32flag);    // ch0, p = 64+lane
            float x11 = ldE(x, sb + 192 + lane, f32flag);
            h16x8 r0 = zrow, r1 = zrow;
            r0[0] = (h16)x00; r0[1] = (h16)x10;
            r1[0] = (h16)x01; r1[1] = (h16)x11;
            *(h16x8*)&V[lane * 8]        = r0;
            *(h16x8*)&V[(64 + lane) * 8] = r1;
            if (lane < 3) *(h16x8*)&V[(128 + lane) * 8] = zrow;  // pad rows 128..130
        }
        LDS_FENCE();

        // ---- conv1 (16x16x32, K pad 4->32): xi8 -> act1 U[2g][127] ----
#pragma unroll
        for (int t = 0; t < 8; ++t) {
            int n = t * 16 + n16;
            f32x4 acc = b1v;
            h16x8 bfr = *(const h16x8*)&V[(n + kg16) * 8];
            acc = __builtin_amdgcn_mfma_f32_16x16x32_f16(a1, bfr, acc, 0, 0, 0);
            if (n < 127) {
                uint2 p = pack4(lrelu(acc[0]), lrelu(acc[1]), lrelu(acc[2]), lrelu(acc[3]));
                *(uint2*)&U[(o16 >> 3) * 1056 + n * 8 + (o16 & 7)] = p;
            }
        }
        // zero act1 pad rows 127..130 (both groups) so conv2's zero-A columns
        // never touch stale/NaN LDS
        if (lane < 8) {
            int g = lane & 1, row = 127 + (lane >> 1);
            *(uint4*)&U[g * 1056 + row * 8] = make_uint4(0, 0, 0, 0);
        }
        LDS_FENCE();

        // ---- conv2 (16x16x32): act1 -> act2 V[2g][125] ----
#pragma unroll
        for (int t = 0; t < 8; ++t) {
            int n = t * 16 + n16;
            f32x4 acc = b2v;
#pragma unroll
            for (int c = 0; c < 2; ++c) {
                int k0 = c * 32 + kg16 * 8;
                int dk = k0 >> 4, g = (k0 & 15) >> 3;
                h16x8 bfr = *(const h16x8*)&U[g * 1056 + (n + dk) * 8];
                acc = __builtin_amdgcn_mfma_f32_16x16x32_f16(a2[c], bfr, acc, 0, 0, 0);
            }
            if (n < 125) {
                uint2 p = pack4(lrelu(acc[0]), lrelu(acc[1]), lrelu(acc[2]), lrelu(acc[3]));
                *(uint2*)&V[(o16 >> 3) * 1008 + n * 8 + (o16 & 7)] = p;
            }
        }
        LDS_FENCE();

        // ---- pool1: act2 -> pooled U[2g][62] ----
        if (lane < 62) {
#pragma unroll
            for (int g = 0; g < 2; ++g) {
                h16x8 pa = *(const h16x8*)&V[g * 1008 + (2 * lane) * 8];
                h16x8 pb = *(const h16x8*)&V[g * 1008 + (2 * lane + 1) * 8];
                h16x8 mm;
#pragma unroll
                for (int e = 0; e < 8; ++e) mm[e] = pa[e] > pb[e] ? pa[e] : pb[e];
                *(h16x8*)&U[g * 1056 + lane * 8] = mm;
            }
        }
        LDS_FENCE();

        // ---- conv3 (32x32x16): pooled -> act3 V[4g][58] ----
#pragma unroll
        for (int t = 0; t < 2; ++t) {
            int n = t * 32 + n32;
            f32x16 acc = {0.f,0.f,0.f,0.f,0.f,0.f,0.f,0.f,0.f,0.f,0.f,0.f,0.f,0.f,0.f,0.f};
#pragma unroll
            for (int c = 0; c < 5; ++c) {
                h16x8 bfr = *(const h16x8*)&U[kg32 * 1056 + (n + c) * 8];
                acc = __builtin_amdgcn_mfma_f32_32x32x16_f16(a3[c], bfr, acc, 0, 0, 0);
            }
            if (n < 58) {
#pragma unroll
                for (int g = 0; g < 4; ++g) {
                    int r0 = 8 * g + 4 * kg32;
                    f32x4 bv = *(const f32x4*)&wsf[96 + r0];
                    uint2 p = pack4(lrelu(acc[4*g+0] + bv[0]), lrelu(acc[4*g+1] + bv[1]),
                                    lrelu(acc[4*g+2] + bv[2]), lrelu(acc[4*g+3] + bv[3]));
                    *(uint2*)&V[g * 552 + n * 8 + 4 * kg32] = p;
                }
            }
        }
        LDS_FENCE();

        // ---- conv4 (32x32x16): act3 -> act4 U[4g][54] ----
#pragma unroll
        for (int t = 0; t < 2; ++t) {
            int n = t * 32 + n32;
            f32x16 acc = {0.f,0.f,0.f,0.f,0.f,0.f,0.f,0.f,0.f,0.f,0.f,0.f,0.f,0.f,0.f,0.f};
#pragma unroll
            for (int c = 0; c < 10; ++c) {
                int k0 = c * 16 + kg32 * 8;
                int dk = k0 >> 5, g = (k0 >> 3) & 3;
                h16x8 bfr = *(const h16x8*)&V[g * 552 + (n + dk) * 8];
                acc = __builtin_amdgcn_mfma_f32_32x32x16_f16(a4[c], bfr, acc, 0, 0, 0);
            }
            if (n < 54) {
#pragma unroll
                for (int g = 0; g < 4; ++g) {
                    int r0 = 8 * g + 4 * kg32;
                    f32x4 bv = *(const f32x4*)&wsf[128 + r0];
                    uint2 p = pack4(lrelu(acc[4*g+0] + bv[0]), lrelu(acc[4*g+1] + bv[1]),
                                    lrelu(acc[4*g+2] + bv[2]), lrelu(acc[4*g+3] + bv[3]));
                    *(uint2*)&U[g * 448 + n * 8 + 4 * kg32] = p;
                }
            }
        }
        LDS_FENCE();

        // ---- pool2 + flatten: act4 -> flatb[slot], phys chunk = g*27 + pos ----
        if (lane < 27) {
#pragma unroll
            for (int g = 0; g < 4; ++g) {
                h16x8 pa = *(const h16x8*)&U[g * 448 + (2 * lane) * 8];
                h16x8 pb = *(const h16x8*)&U[g * 448 + (2 * lane + 1) * 8];
                h16x8 mm;
#pragma unroll
                for (int e = 0; e < 8; ++e) mm[e] = pa[e] > pb[e] ? pa[e] : pb[e];
                *(h16x8*)&flatb[slot][(g * 27 + lane) * 8] = mm;
            }
        }
    }
    __syncthreads();

    // ---- dense (16x16x32): flatb[8][864] @ FD, wave w = m-tile ----
    int o0g = w * 16 + o16;
    f32x4 dacc = *(const f32x4*)&wsf[160 + o0g];  // bias in C
    for (int c = 0; c < 27; ++c) {
        h16x8 aw = *(const h16x8*)&FDg[((w * 27 + c) * 64 + lane) * 8];
        h16x8 bh = *(const h16x8*)&flatb[lane & 7][(kg16 * 27 + c) * 8];
        dacc = __builtin_amdgcn_mfma_f32_16x16x32_f16(aw, bh, dacc, 0, 0, 0);
    }
    f32x4 qov = *(const f32x4*)&wsf[224 + o0g];
    float part = 0.f;
#pragma unroll
    for (int q = 0; q < 4; ++q) part += lrelu(dacc[q]) * qov[q];
    red[tid] = part;
    __syncthreads();
    if (tid < 8) {
        float y = wsf[288];
#pragma unroll
        for (int g = 0; g < 16; ++g) y += red[(g >> 2) * 64 + (g & 3) * 16 + tid];
        if (f32flag) ((float*)out)[b0 + tid] = y;
        else         ((bf16*)out)[b0 + tid] = __float2bfloat16(y);
    }
}

extern "C" void kernel_launch(void* const* d_in, const int* in_sizes, int n_in,
                              void* d_out, int out_size, void* d_ws, size_t ws_size,
                              hipStream_t stream) {
    const void* x  = d_in[0];
    const void* w1 = d_in[1];
    const void* b1 = d_in[2];
    const void* w2 = d_in[3];
    const void* b2 = d_in[4];
    const void* w3 = d_in[5];
    const void* b3 = d_in[6];
    const void* w4 = d_in[7];
    const void* b4 = d_in[8];
    const void* wd = d_in[9];
    const void* bd = d_in[10];
    const void* wo = d_in[11];
    const void* bo = d_in[12];
    float* wsf = (float*)d_ws;

    int B = in_sizes[0] / 256;            // 32768
    prep<<<57, 256, 0, stream>>>((const unsigned short*)x,
                                 w1, w2, w3, w4, wd, wo,
                                 b1, b2, b3, b4, bd, bo, wsf);
    qcnn_main<<<B / 8, 256, 0, stream>>>(x, wsf, d_out);
}